// Round 5
// baseline (108.326 us; speedup 1.0000x reference)
//
#include <hip/hip_runtime.h>
#include <utility>

#define FIELD 39
#define TILE  13      // 3 tiles of 13
#define DIM   16
#define BATCH 8192
#define EPAD  42      // 39 real + 3 zero pad (padded-row FMAs may index up to 41)

// ---- compile-time weight layout: block-padded, every row 16B-aligned ----
constexpr int widx(int i, int j) { return i*(FIELD-1) - i*(i-1)/2 + (j-i-1); }
constexpr int ceil4(int x) { return (x+3) & ~3; }
constexpr int OFF_ROW  = 16;                 // off-diag row padded 13 -> 16
constexpr int OFF_TILE = TILE * OFF_ROW;     // 208
constexpr int diag_rowstart(int II) {        // triangular rows, padded to x4
    int s = 0; for (int m = 0; m < II; ++m) s += ceil4(TILE-1-m); return s;
}
constexpr int DIAG_TILE = diag_rowstart(TILE);          // 96
constexpr int off_base(int t) { return t * OFF_TILE; }  // t: 0=(0,1) 1=(0,2) 2=(1,2)
constexpr int diag_base(int A) { return 3*OFF_TILE + A*DIAG_TILE; }
constexpr int WTOT = 3*OFF_TILE + 3*DIAG_TILE;          // 912 floats = 3.6 KB

struct WMap { int v[WTOT]; };
constexpr WMap make_map() {
    WMap m{};
    for (int i = 0; i < WTOT; ++i) m.v[i] = -1;          // -1 -> 0.0f pad
    const int AB[3][2] = {{0,1},{0,2},{1,2}};
    for (int t = 0; t < 3; ++t)
        for (int II = 0; II < TILE; ++II)
            for (int c = 0; c < TILE; ++c)
                m.v[off_base(t) + II*OFF_ROW + c] = widx(AB[t][0]*TILE+II, AB[t][1]*TILE+c);
    for (int A = 0; A < 3; ++A)
        for (int II = 0; II < TILE-1; ++II)
            for (int k = 0; k < TILE-1-II; ++k)
                m.v[diag_base(A) + diag_rowstart(II) + k] = widx(A*TILE+II, A*TILE+II+1+k);
    return m;
}
__device__ constexpr WMap g_map = make_map();

// ---- compute machinery: every index a literal after instantiation ----
__device__ __forceinline__ float4 ld4(const float* lds, int ofs) {
    return *reinterpret_cast<const float4*>(lds + ofs);   // ds_read_b128, imm offset
}
template <int EB>
__device__ __forceinline__ float fma4(float4 w, const float (&e)[EPAD], float s) {
    s = fmaf(w.x, e[EB+0], s); s = fmaf(w.y, e[EB+1], s);
    s = fmaf(w.z, e[EB+2], s); s = fmaf(w.w, e[EB+3], s);
    return s;
}
template <int RBASE, int EBASE, size_t... Qs>
__device__ __forceinline__ float row_q(const float* lds, const float (&e)[EPAD],
                                       std::index_sequence<Qs...>) {
    float s = 0.f;
    ((s = fma4<EBASE + 4*(int)Qs>(ld4(lds, RBASE + 4*(int)Qs), e, s)), ...);
    return s;
}
template <int T, int A, int B, size_t... IIs>   // off-diagonal 13x13 block
__device__ __forceinline__ void block_off(const float* lds, const float (&e)[EPAD],
                                          float (&acc)[4], std::index_sequence<IIs...>) {
    ((acc[IIs & 3] = fmaf(e[A*TILE + (int)IIs],
         row_q<off_base(T) + (int)IIs*OFF_ROW, B*TILE>(lds, e, std::make_index_sequence<4>{}),
         acc[IIs & 3])), ...);
}
template <int A, size_t... IIs>                 // diagonal triangular block
__device__ __forceinline__ void block_diag(const float* lds, const float (&e)[EPAD],
                                           float (&acc)[4], std::index_sequence<IIs...>) {
    ((acc[IIs & 3] = fmaf(e[A*TILE + (int)IIs],
         row_q<diag_base(A) + diag_rowstart((int)IIs), A*TILE + (int)IIs + 1>(
             lds, e, std::make_index_sequence<(size_t)(ceil4(TILE-1-(int)IIs)/4)>{}),
         acc[IIs & 3])), ...);
}
template <size_t... Fs>
__device__ __forceinline__ void gather_all(const int* __restrict__ rowIdx,
                                           const float* __restrict__ emb,
                                           int d, float (&e)[EPAD],
                                           std::index_sequence<Fs...>) {
    int idx[FIELD];
    ((idx[Fs] = rowIdx[Fs]), ...);                        // merged dwordx4
    ((e[Fs] = emb[(size_t)idx[Fs] * DIM + d]), ...);      // 39 independent gathers
}

// One wave = 4 rows; lane = rloc*16 + d. e[] in VGPRs; fw in LDS, read as
// aligned float4 broadcasts with immediate offsets (pipelined ds_read_b128).
__global__ __launch_bounds__(256, 2) void fwfm_kernel(
    const int*   __restrict__ inputs,   // [BATCH][FIELD]
    const float* __restrict__ emb,      // [1M][DIM]
    const float* __restrict__ fw,       // [741]
    const float* __restrict__ lw,       // [1M]
    const float* __restrict__ bias,     // [1]
    float*       __restrict__ out)      // [BATCH]
{
    __shared__ __align__(16) float wlds[WTOT];

    const int tid  = threadIdx.x;
    const int lane = tid & 63;
    const int wave = tid >> 6;
    const int d    = lane & 15;
    const int rloc = lane >> 4;
    const int row  = blockIdx.x * 16 + wave * 4 + rloc;

    const int* rowIdx = inputs + row * FIELD;

    // ---- issue the long-latency gathers first ----
    float e[EPAD];
    gather_all(rowIdx, emb, d, e, std::make_index_sequence<FIELD>{});
    e[39] = 0.f; e[40] = 0.f; e[41] = 0.f;

    // ---- stage packed weights into LDS (overlaps gather latency) ----
    for (int s = tid; s < WTOT; s += 256) {
        int m = g_map.v[s];
        wlds[s] = (m >= 0) ? fw[m] : 0.f;
    }
    __syncthreads();

    // ---- first order: 39 fields split across the 16 dim-lanes ----
    float fo = lw[rowIdx[d]] + lw[rowIdx[d + 16]];
    if (d < 7) fo += lw[rowIdx[d + 32]];

    // ---- second order over 6 tile blocks ----
    float acc[4] = {0.f, 0.f, 0.f, 0.f};
    const auto seqT = std::make_index_sequence<TILE>{};
    block_off<0, 0, 1>(wlds, e, acc, seqT);
    block_off<1, 0, 2>(wlds, e, acc, seqT);
    block_off<2, 1, 2>(wlds, e, acc, seqT);
    block_diag<0>(wlds, e, acc, seqT);
    block_diag<1>(wlds, e, acc, seqT);
    block_diag<2>(wlds, e, acc, seqT);
    float so = (acc[0] + acc[1]) + (acc[2] + acc[3]);

    // ---- reduce the 16 dim-lanes of this row ----
    float tot = fo + so;
    tot += __shfl_xor(tot, 1, 64);
    tot += __shfl_xor(tot, 2, 64);
    tot += __shfl_xor(tot, 4, 64);
    tot += __shfl_xor(tot, 8, 64);

    if (d == 0) out[row] = tot + bias[0];
}

extern "C" void kernel_launch(void* const* d_in, const int* in_sizes, int n_in,
                              void* d_out, int out_size, void* d_ws, size_t ws_size,
                              hipStream_t stream) {
    const int*   inputs = (const int*)  d_in[0];
    const float* emb    = (const float*)d_in[1];
    const float* fw     = (const float*)d_in[2];
    const float* lw     = (const float*)d_in[3];
    const float* bias   = (const float*)d_in[4];
    float*       out    = (float*)      d_out;

    dim3 grid(BATCH / 16);   // 512 blocks * 4 waves * 4 rows = 8192 rows
    fwfm_kernel<<<grid, 256, 0, stream>>>(inputs, emb, fw, lw, bias, out);
}